// Round 4
// baseline (1124.535 us; speedup 1.0000x reference)
//
#include <hip/hip_runtime.h>
#include <math.h>

typedef unsigned short u16;
typedef __bf16 bf16x8 __attribute__((ext_vector_type(8)));
typedef float f32x4 __attribute__((ext_vector_type(4)));

__device__ __forceinline__ float b2f(u16 u) { return __uint_as_float(((unsigned)u) << 16); }
__device__ __forceinline__ u16 f2b(float f) {
    unsigned x = __float_as_uint(f);
    return (u16)((x + 0x7FFFu + ((x >> 16) & 1u)) >> 16);
}

// fp32 8-element vector load (two float4s); idx multiple of 8
__device__ __forceinline__ void load8f(const float* p, size_t idx, float* o) {
    const float4* q = (const float4*)(p + idx);
    float4 a = q[0], b = q[1];
    o[0]=a.x; o[1]=a.y; o[2]=a.z; o[3]=a.w; o[4]=b.x; o[5]=b.y; o[6]=b.z; o[7]=b.w;
}

// window-order row r -> token-order row of hidden (applies roll(-5,-5) + window partition)
__device__ __forceinline__ int win2tok(int r) {
    int b = r / 4800, rem = r - b * 4800;
    int widx = rem / 100, l = rem - widx * 100;
    int wh = widx / 6, ww = widx - wh * 6;
    int i = l / 10, j = l - i * 10;
    int h = wh * 10 + i + 5; if (h >= 80) h -= 80;
    int w = ww * 10 + j + 5; if (w >= 60) w -= 60;
    return b * 4800 + h * 60 + w;
}

// ---------------- weight transpose+convert: Wt[n][k] = bf16(W[k][n]) ----------------
__global__ __launch_bounds__(256) void transpose_k(const float* __restrict__ Win, u16* __restrict__ Wt,
                                                   int Kd, int Nd) {
    __shared__ u16 tile[32][33];
    int tx = threadIdx.x & 31, ty = threadIdx.x >> 5;   // 32 x 8
    int k0 = blockIdx.x << 5, n0 = blockIdx.y << 5;
#pragma unroll
    for (int r = 0; r < 4; r++)
        tile[ty + 8 * r][tx] = f2b(Win[(size_t)(k0 + ty + 8 * r) * Nd + (n0 + tx)]);
    __syncthreads();
#pragma unroll
    for (int r = 0; r < 4; r++)
        Wt[(size_t)(n0 + ty + 8 * r) * Kd + (k0 + tx)] = tile[tx][ty + 8 * r];
}

// ---------------- per-token LN1 stats over hidden (token order) ----------------
__global__ __launch_bounds__(256) void stats1_k(const float* __restrict__ x, float2* __restrict__ st) {
    int wave = threadIdx.x >> 6, lane = threadIdx.x & 63;
    int t = blockIdx.x * 4 + wave;
    float v[8]; load8f(x, (size_t)t * 512 + lane * 8, v);
    float s = 0.f, s2 = 0.f;
#pragma unroll
    for (int e = 0; e < 8; e++) { s += v[e]; s2 += v[e] * v[e]; }
#pragma unroll
    for (int o = 32; o > 0; o >>= 1) { s += __shfl_xor(s, o); s2 += __shfl_xor(s2, o); }
    float mean = s * (1.0f / 512.0f);
    float var = fmaxf(s2 * (1.0f / 512.0f) - mean * mean, 0.0f);
    if (lane == 0) st[t] = make_float2(mean, rsqrtf(var + 1e-5f));
}

// ---------------- window reverse + residual + LN2 stats: hs = shortcut + unwin(attn_out) ----------------
__global__ __launch_bounds__(256) void resid_k(const float* __restrict__ shortcut, const u16* __restrict__ attn_out,
                                               u16* __restrict__ hs, float2* __restrict__ st) {
    int wave = threadIdx.x >> 6, lane = threadIdx.x & 63;
    int token = blockIdx.x * 4 + wave;
    int b = token / 4800, rem = token - b * 4800;
    int h = rem / 60, w = rem - h * 60;
    int h2 = h + 75; if (h2 >= 80) h2 -= 80;    // (h-5) mod 80
    int w2 = w + 55; if (w2 >= 60) w2 -= 60;    // (w-5) mod 60
    int widx = (h2 / 10) * 6 + (w2 / 10);
    int l = (h2 - (h2 / 10) * 10) * 10 + (w2 - (w2 / 10) * 10);
    size_t arow = ((size_t)b * 48 + widx) * 100 + l;
    int c0 = lane * 8;
    float sv[8]; load8f(shortcut, (size_t)token * 512 + c0, sv);
    uint4 da = *(const uint4*)(attn_out + arow * 512 + c0);
    const u16* au = (const u16*)&da;
    float s = 0.f, s2 = 0.f;
    uint4 o; u16* ou = (u16*)&o;
#pragma unroll
    for (int e = 0; e < 8; e++) {
        float hv = sv[e] + b2f(au[e]);
        s += hv; s2 += hv * hv;
        ou[e] = f2b(hv);
    }
    *(uint4*)(hs + (size_t)token * 512 + c0) = o;
#pragma unroll
    for (int off = 32; off > 0; off >>= 1) { s += __shfl_xor(s, off); s2 += __shfl_xor(s2, off); }
    float mean = s * (1.0f / 512.0f);
    float var = fmaxf(s2 * (1.0f / 512.0f) - mean * mean, 0.0f);
    if (lane == 0) st[token] = make_float2(mean, rsqrtf(var + 1e-5f));
}

// ---------------- MFMA GEMM: C = epi(Astage(A)[M,K] @ Bt[N,K]^T + bias) ----------------
// AMODE: 0 = A is bf16 plain; 1 = A = fp32 hidden, window-order rows remapped + LN1;
//        2 = A = bf16 hs + LN2
// EPI:   0 = bias; 1 = bias + exact GELU; 2 = bias + residual add (res bf16 [M,N])
// OF32:  0 = C is bf16 (u16); 1 = C is fp32 (float)
template <int EPI, int AMODE, int OF32>
__global__ __launch_bounds__(256) void gemm_k(const void* __restrict__ A, const u16* __restrict__ Bt,
                                              const float* __restrict__ bias, const u16* __restrict__ res,
                                              void* __restrict__ C,
                                              const float2* __restrict__ st,
                                              const float* __restrict__ lng, const float* __restrict__ lnb,
                                              int M, int N, int K) {
    __shared__ __align__(16) u16 As[128 * 40];  // stride 40: byte-stride 80 -> 2-way bank alias (free)
    __shared__ __align__(16) u16 Bs[128 * 40];
    int tid = threadIdx.x;
    int wave = tid >> 6, lane = tid & 63;
    int l15 = lane & 15, quad = lane >> 4;
    int wm = (wave >> 1) * 64, wn = (wave & 1) * 64;
    int bm = blockIdx.x, bn = blockIdx.y;
    int srow = tid >> 2, scol = (tid & 3) * 8;   // staging: 4 threads/row, 8 elems each

    f32x4 acc[4][4];
#pragma unroll
    for (int i = 0; i < 4; i++)
#pragma unroll
        for (int j = 0; j < 4; j++) acc[i][j] = (f32x4){0.f, 0.f, 0.f, 0.f};

    int r0 = bm * 128 + srow, r1 = r0 + 64;
    size_t arow[2]; float mean[2], rstd[2];
    if (AMODE == 1) {
        int t0 = win2tok(r0), t1 = win2tok(r1);
        arow[0] = (size_t)t0 * 512; arow[1] = (size_t)t1 * 512;
        float2 s0 = st[t0], s1 = st[t1];
        mean[0] = s0.x; rstd[0] = s0.y; mean[1] = s1.x; rstd[1] = s1.y;
    } else {
        arow[0] = (size_t)r0 * K; arow[1] = (size_t)r1 * K;
        if (AMODE == 2) {
            float2 s0 = st[r0], s1 = st[r1];
            mean[0] = s0.x; rstd[0] = s0.y; mean[1] = s1.x; rstd[1] = s1.y;
        }
    }
    const u16* Bblk = Bt + (size_t)(bn * 128) * K;

    for (int kt = 0; kt < K; kt += 32) {
        if (AMODE == 0) {
#pragma unroll
            for (int hh = 0; hh < 2; hh++)
                *(uint4*)(&As[(srow + 64 * hh) * 40 + scol]) =
                    *(const uint4*)((const u16*)A + arow[hh] + kt + scol);
        } else {
            float g8[8], bb8[8];
            load8f(lng, kt + scol, g8);
            load8f(lnb, kt + scol, bb8);
#pragma unroll
            for (int hh = 0; hh < 2; hh++) {
                float x8[8];
                if (AMODE == 1) load8f((const float*)A, arow[hh] + kt + scol, x8);
                else {
                    uint4 d = *(const uint4*)((const u16*)A + arow[hh] + kt + scol);
                    const u16* du = (const u16*)&d;
#pragma unroll
                    for (int e = 0; e < 8; e++) x8[e] = b2f(du[e]);
                }
                uint4 pk; u16* pu = (u16*)&pk;
#pragma unroll
                for (int e = 0; e < 8; e++)
                    pu[e] = f2b((x8[e] - mean[hh]) * rstd[hh] * g8[e] + bb8[e]);
                *(uint4*)(&As[(srow + 64 * hh) * 40 + scol]) = pk;
            }
        }
#pragma unroll
        for (int hh = 0; hh < 2; hh++) {
            int rr = srow + 64 * hh;
            *(uint4*)(&Bs[rr * 40 + scol]) = *(const uint4*)(Bblk + (size_t)rr * K + kt + scol);
        }
        __syncthreads();
        bf16x8 af[4], bfr[4];
#pragma unroll
        for (int t = 0; t < 4; t++) {
            af[t]  = *(const bf16x8*)(&As[(wm + t * 16 + l15) * 40 + quad * 8]);
            bfr[t] = *(const bf16x8*)(&Bs[(wn + t * 16 + l15) * 40 + quad * 8]);
        }
#pragma unroll
        for (int i = 0; i < 4; i++)
#pragma unroll
            for (int j = 0; j < 4; j++)
                acc[i][j] = __builtin_amdgcn_mfma_f32_16x16x32_bf16(af[i], bfr[j], acc[i][j], 0, 0, 0);
        __syncthreads();
    }

    // C/D layout: col = lane&15, row = quad*4 + reg (verified m89/m91)
#pragma unroll
    for (int i = 0; i < 4; i++) {
        int row0 = bm * 128 + wm + i * 16 + quad * 4;
#pragma unroll
        for (int j = 0; j < 4; j++) {
            int col = bn * 128 + wn + j * 16 + l15;
            float bv = bias[col];
#pragma unroll
            for (int rr = 0; rr < 4; rr++) {
                int row = row0 + rr;
                float v = acc[i][j][rr] + bv;
                if (EPI == 1) v = 0.5f * v * (1.0f + erff(v * 0.70710678118654752f));
                if (EPI == 2) v += b2f(res[(size_t)row * N + col]);
                if (OF32) ((float*)C)[(size_t)row * N + col] = v;
                else      ((u16*)C)[(size_t)row * N + col] = f2b(v);
            }
        }
    }
}

// ---------------- windowed attention: one block per (window, head) ----------------
// ctx may alias Km: block (w,h) touches only rows of window w / cols of head h;
// all global K reads complete before the barrier, ctx writes after -> safe.
__global__ __launch_bounds__(128) void attn_k(const u16* __restrict__ Q, const u16* __restrict__ Km,
                                              const u16* __restrict__ V, const float* __restrict__ table,
                                              u16* __restrict__ ctx) {
    __shared__ float Ks[3200];
    __shared__ float Vs[3200];
    int bid = blockIdx.x;
    int win = bid >> 4, head = bid & 15;
    int w48 = win % 48;
    int wh = w48 / 6, ww = w48 - wh * 6;
    int tid = threadIdx.x;
    size_t base = (size_t)win * 100 * 512 + head * 32;
    for (int vi = tid; vi < 400; vi += 128) {
        int kk = vi >> 2, d0 = (vi & 3) * 8;
        uint4 dk = *(const uint4*)(Km + base + (size_t)kk * 512 + d0);
        uint4 dv = *(const uint4*)(V + base + (size_t)kk * 512 + d0);
        const u16* ku = (const u16*)&dk; const u16* vu = (const u16*)&dv;
#pragma unroll
        for (int t = 0; t < 8; t++) { Ks[kk * 32 + d0 + t] = b2f(ku[t]); Vs[kk * 32 + d0 + t] = b2f(vu[t]); }
    }
    __syncthreads();
    int q = tid;
    if (q >= 100) return;
    float qr[32];
    {
        const u16* qp = Q + base + (size_t)q * 512;
#pragma unroll
        for (int t = 0; t < 4; t++) {
            uint4 dq = *(const uint4*)(qp + t * 8);
            const u16* qu = (const u16*)&dq;
#pragma unroll
            for (int e = 0; e < 8; e++) qr[t * 8 + e] = b2f(qu[e]) * 0.17677669529663689f; // 1/sqrt(32)
        }
    }
    int qi = q / 10, qj = q - qi * 10;
    int qoff = qi * 19 + qj;
    // analytic Swin shift-mask regions (HF convention)
    int rhq = (wh == 7) ? (qi < 5 ? 1 : 2) : 0;
    int rwq = (ww == 5) ? (qj < 5 ? 1 : 2) : 0;
    float s[100];
#pragma unroll
    for (int k = 0; k < 100; k++) {
        const int ki = k / 10, kj = k % 10;
        float a = 0.f;
#pragma unroll
        for (int d = 0; d < 32; d++) a += qr[d] * Ks[k * 32 + d];
        a += table[(qoff - (ki * 19 + kj) + 180) * 16 + head];
        int rhk = (wh == 7) ? (ki < 5 ? 1 : 2) : 0;
        int rwk = (ww == 5) ? (kj < 5 ? 1 : 2) : 0;
        if ((rhk != rhq) | (rwk != rwq)) a -= 100.f;
        s[k] = a;
    }
    float m = s[0];
#pragma unroll
    for (int k = 1; k < 100; k++) m = fmaxf(m, s[k]);
    float sum = 0.f;
#pragma unroll
    for (int k = 0; k < 100; k++) { float e = __expf(s[k] - m); s[k] = e; sum += e; }
    float inv = 1.0f / sum;
    float o[32];
#pragma unroll
    for (int d = 0; d < 32; d++) o[d] = 0.f;
#pragma unroll
    for (int k = 0; k < 100; k++) {
        float p = s[k];
#pragma unroll
        for (int d = 0; d < 32; d++) o[d] += p * Vs[k * 32 + d];
    }
    u16* cp = ctx + base + (size_t)q * 512;
#pragma unroll
    for (int t = 0; t < 4; t++) {
        uint4 ov; u16* ou = (u16*)&ov;
#pragma unroll
        for (int e = 0; e < 8; e++) ou[e] = f2b(o[t * 8 + e] * inv);
        *(uint4*)(cp + t * 8) = ov;
    }
}

extern "C" void kernel_launch(void* const* d_in, const int* in_sizes, int n_in,
                              void* d_out, int out_size, void* d_ws, size_t ws_size,
                              hipStream_t stream) {
    const float* hidden = (const float*)d_in[0];
    const float* ln1_g  = (const float*)d_in[1];
    const float* ln1_b  = (const float*)d_in[2];
    const float* wq = (const float*)d_in[3];  const float* bq = (const float*)d_in[4];
    const float* wk = (const float*)d_in[5];  const float* bk = (const float*)d_in[6];
    const float* wv = (const float*)d_in[7];  const float* bv = (const float*)d_in[8];
    const float* wo = (const float*)d_in[9];  const float* bo = (const float*)d_in[10];
    const float* rel = (const float*)d_in[11];
    const float* ln2_g = (const float*)d_in[12];
    const float* ln2_b = (const float*)d_in[13];
    const float* w1 = (const float*)d_in[14]; const float* b1 = (const float*)d_in[15];
    const float* w2 = (const float*)d_in[16]; const float* b2 = (const float*)d_in[17];

    // Workspace (~85.6 MiB):
    //   R0 [0,NTC)     : q -> attn_out -> ffn1 chunk (9600x2048 bf16 == NTC)
    //   R1 [NTC,2NTC)  : k -> ctx (aliased in attn) -> hs
    //   d_out (fp32, 78.6MB): V parked as bf16 during attention; final fp32 output
    //   weights/stats after 2NTC
    const size_t NTC = 38400ull * 512;
    u16* ws = (u16*)d_ws;
    u16* R0 = ws;
    u16* R1 = ws + NTC;
    u16* wqt = ws + 2 * NTC;
    u16* wkt = wqt + 512 * 512;
    u16* wvt = wkt + 512 * 512;
    u16* wot = wvt + 512 * 512;
    u16* w1t = wot + 512 * 512;      // (2048,512)
    u16* w2t = w1t + 1048576;        // (512,2048)
    float2* st1 = (float2*)(w2t + 1048576);
    float2* st2 = st1 + 38400;
    u16* vb = (u16*)d_out;           // V as bf16, dead before fp32 output writes
    float* outp = (float*)d_out;

    transpose_k<<<dim3(16, 16), 256, 0, stream>>>(wq, wqt, 512, 512);
    transpose_k<<<dim3(16, 16), 256, 0, stream>>>(wk, wkt, 512, 512);
    transpose_k<<<dim3(16, 16), 256, 0, stream>>>(wv, wvt, 512, 512);
    transpose_k<<<dim3(16, 16), 256, 0, stream>>>(wo, wot, 512, 512);
    transpose_k<<<dim3(16, 64), 256, 0, stream>>>(w1, w1t, 512, 2048);
    transpose_k<<<dim3(64, 16), 256, 0, stream>>>(w2, w2t, 2048, 512);

    stats1_k<<<9600, 256, 0, stream>>>(hidden, st1);

    // QKV: A = fp32 hidden (window-remapped + LN1 in staging)
    gemm_k<0, 1, 0><<<dim3(300, 4), 256, 0, stream>>>(hidden, wqt, bq, nullptr, R0,
                                                      st1, ln1_g, ln1_b, 38400, 512, 512);
    gemm_k<0, 1, 0><<<dim3(300, 4), 256, 0, stream>>>(hidden, wkt, bk, nullptr, R1,
                                                      st1, ln1_g, ln1_b, 38400, 512, 512);
    gemm_k<0, 1, 0><<<dim3(300, 4), 256, 0, stream>>>(hidden, wvt, bv, nullptr, vb,
                                                      st1, ln1_g, ln1_b, 38400, 512, 512);

    // attention: ctx aliases K (R1)
    attn_k<<<6144, 128, 0, stream>>>(R0, R1, vb, rel, R1 /*ctx*/);

    // WO projection: ctx(R1) -> attn_out(R0)
    gemm_k<0, 0, 0><<<dim3(300, 4), 256, 0, stream>>>(R1, wot, bo, nullptr, R0,
                                                      nullptr, nullptr, nullptr, 38400, 512, 512);

    // window reverse + residual + LN2 stats: hs -> R1 (bf16)
    resid_k<<<9600, 256, 0, stream>>>(hidden, R0, R1, st2);

    // FFN chunked over M: 4 chunks of 9600 rows; h1 chunk (9600x2048 bf16) in R0
    for (int mc = 0; mc < 4; mc++) {
        size_t roff = (size_t)mc * 9600 * 512;
        gemm_k<1, 2, 0><<<dim3(75, 16), 256, 0, stream>>>(R1 + roff, w1t, b1, nullptr, R0,
                                                          st2 + mc * 9600, ln2_g, ln2_b,
                                                          9600, 2048, 512);
        gemm_k<2, 0, 1><<<dim3(75, 4), 256, 0, stream>>>(R0, w2t, b2, R1 + roff, outp + roff,
                                                         nullptr, nullptr, nullptr,
                                                         9600, 512, 2048);
    }
}

// Round 5
// 1033.181 us; speedup vs baseline: 1.0884x; 1.0884x over previous
//
#include <hip/hip_runtime.h>
#include <math.h>

typedef unsigned short u16;
typedef unsigned int u32;
typedef __bf16 bf16x8 __attribute__((ext_vector_type(8)));
typedef float f32x4 __attribute__((ext_vector_type(4)));

__device__ __forceinline__ float b2f(u16 u) { return __uint_as_float(((u32)u) << 16); }
__device__ __forceinline__ u16 f2b(float f) {
    u32 x = __float_as_uint(f);
    return (u16)((x + 0x7FFFu + ((x >> 16) & 1u)) >> 16);
}
__device__ __forceinline__ void load8f(const float* p, size_t idx, float* o) {
    const float4* q = (const float4*)(p + idx);
    float4 a = q[0], b = q[1];
    o[0]=a.x; o[1]=a.y; o[2]=a.z; o[3]=a.w; o[4]=b.x; o[5]=b.y; o[6]=b.z; o[7]=b.w;
}
// async global->LDS, 16B per lane; LDS dest = wave-uniform base + lane*16
__device__ __forceinline__ void gld16(const void* g, void* l) {
    __builtin_amdgcn_global_load_lds(
        (const __attribute__((address_space(1))) u32*)g,
        (__attribute__((address_space(3))) u32*)l, 16, 0, 0);
}

// ---------------- weight transpose+convert: Wt[n][k] = bf16(W[k][n]) ----------------
__global__ __launch_bounds__(256) void transpose_k(const float* __restrict__ Win, u16* __restrict__ Wt,
                                                   int Kd, int Nd) {
    __shared__ u16 tile[32][33];
    int tx = threadIdx.x & 31, ty = threadIdx.x >> 5;
    int k0 = blockIdx.x << 5, n0 = blockIdx.y << 5;
#pragma unroll
    for (int r = 0; r < 4; r++)
        tile[ty + 8 * r][tx] = f2b(Win[(size_t)(k0 + ty + 8 * r) * Nd + (n0 + tx)]);
    __syncthreads();
#pragma unroll
    for (int r = 0; r < 4; r++)
        Wt[(size_t)(n0 + ty + 8 * r) * Kd + (k0 + tx)] = tile[tx][ty + 8 * r];
}

// ---------------- LN1 (stats fused) + shift + window partition: token-order iteration ----------------
__global__ __launch_bounds__(256) void ln1win_k(const float* __restrict__ x, const float* __restrict__ g,
                                                const float* __restrict__ bta, u16* __restrict__ win) {
    int wave = threadIdx.x >> 6, lane = threadIdx.x & 63;
    int token = blockIdx.x * 4 + wave;                  // token-order row
    int b = token / 4800, rem = token - b * 4800;
    int h = rem / 60, w = rem - h * 60;
    int hr = h + 75; if (hr >= 80) hr -= 80;            // (h-5) mod 80 : rolled coord
    int wr = w + 55; if (wr >= 60) wr -= 60;
    int widx = (hr / 10) * 6 + (wr / 10);
    int l = (hr - (hr / 10) * 10) * 10 + (wr - (wr / 10) * 10);
    size_t dstrow = ((size_t)b * 48 + widx) * 100 + l;  // window-order row
    int c0 = lane * 8;
    float v[8]; load8f(x, (size_t)token * 512 + c0, v);
    float s = 0.f, s2 = 0.f;
#pragma unroll
    for (int e = 0; e < 8; e++) { s += v[e]; s2 += v[e] * v[e]; }
#pragma unroll
    for (int o = 32; o > 0; o >>= 1) { s += __shfl_xor(s, o); s2 += __shfl_xor(s2, o); }
    float mean = s * (1.0f / 512.0f);
    float var = fmaxf(s2 * (1.0f / 512.0f) - mean * mean, 0.0f);
    float rstd = rsqrtf(var + 1e-5f);
    uint4 o4; u16* ou = (u16*)&o4;
#pragma unroll
    for (int e = 0; e < 8; e++)
        ou[e] = f2b((v[e] - mean) * rstd * g[c0 + e] + bta[c0 + e]);
    *(uint4*)(win + dstrow * 512 + c0) = o4;
}

// ---------------- window reverse + residual + fused LN2: hs, ln2y ----------------
__global__ __launch_bounds__(256) void resid2_k(const float* __restrict__ shortcut, const u16* __restrict__ attn_out,
                                                const float* __restrict__ g, const float* __restrict__ bta,
                                                u16* __restrict__ hs, u16* __restrict__ ln2y) {
    int wave = threadIdx.x >> 6, lane = threadIdx.x & 63;
    int token = blockIdx.x * 4 + wave;
    int b = token / 4800, rem = token - b * 4800;
    int h = rem / 60, w = rem - h * 60;
    int hr = h + 75; if (hr >= 80) hr -= 80;
    int wr = w + 55; if (wr >= 60) wr -= 60;
    int widx = (hr / 10) * 6 + (wr / 10);
    int l = (hr - (hr / 10) * 10) * 10 + (wr - (wr / 10) * 10);
    size_t arow = ((size_t)b * 48 + widx) * 100 + l;
    int c0 = lane * 8;
    float sv[8]; load8f(shortcut, (size_t)token * 512 + c0, sv);
    uint4 da = *(const uint4*)(attn_out + arow * 512 + c0);
    const u16* au = (const u16*)&da;
    float hv[8]; float s = 0.f, s2 = 0.f;
    uint4 oh; u16* ohu = (u16*)&oh;
#pragma unroll
    for (int e = 0; e < 8; e++) {
        hv[e] = sv[e] + b2f(au[e]);
        s += hv[e]; s2 += hv[e] * hv[e];
        ohu[e] = f2b(hv[e]);
    }
    *(uint4*)(hs + (size_t)token * 512 + c0) = oh;
#pragma unroll
    for (int off = 32; off > 0; off >>= 1) { s += __shfl_xor(s, off); s2 += __shfl_xor(s2, off); }
    float mean = s * (1.0f / 512.0f);
    float var = fmaxf(s2 * (1.0f / 512.0f) - mean * mean, 0.0f);
    float rstd = rsqrtf(var + 1e-5f);
    uint4 oy; u16* oyu = (u16*)&oy;
#pragma unroll
    for (int e = 0; e < 8; e++)
        oyu[e] = f2b((hv[e] - mean) * rstd * g[c0 + e] + bta[c0 + e]);
    *(uint4*)(ln2y + (size_t)token * 512 + c0) = oy;
}

// ---------------- MFMA GEMM (m97-style): C = epi(A[M,K] @ Bt[N,K]^T + bias) ----------------
// EPI: 0 = bias; 1 = bias + tanh-GELU; 2 = bias + residual add (res bf16 [M,512])
// OF32: output fp32 instead of bf16
template <int EPI, int OF32>
__global__ __launch_bounds__(256) void gemm_k(const u16* __restrict__ A, const u16* __restrict__ Bt,
                                              const float* __restrict__ bias, const u16* __restrict__ res,
                                              void* __restrict__ C, int M, int N, int K) {
    __shared__ __align__(16) u16 As[128 * 32];   // unpadded: required by global_load_lds lane mapping
    __shared__ __align__(16) u16 Bs[128 * 32];
    int tid = threadIdx.x;
    int wave = tid >> 6, lane = tid & 63;
    int l15 = lane & 15, quad = lane >> 4;
    int lq = lane >> 2, lr = lane & 3;           // 16 rows x 4 16B-chunks per wave round
    int wm = (wave >> 1) * 64, wn = (wave & 1) * 64;
    int bm = blockIdx.x, bn = blockIdx.y;

    f32x4 acc[4][4];
#pragma unroll
    for (int i = 0; i < 4; i++)
#pragma unroll
        for (int j = 0; j < 4; j++) acc[i][j] = (f32x4){0.f, 0.f, 0.f, 0.f};

    const u16* Ab = A + (size_t)(bm * 128) * K;
    const u16* Bb = Bt + (size_t)(bn * 128) * K;

    for (int kt = 0; kt < K; kt += 32) {
#pragma unroll
        for (int h = 0; h < 2; h++) {
            int r = h * 64 + wave * 16 + lq;
            gld16(Ab + (size_t)r * K + kt + lr * 8, &As[(h * 64 + wave * 16) * 32]);
            gld16(Bb + (size_t)r * K + kt + lr * 8, &Bs[(h * 64 + wave * 16) * 32]);
        }
        __syncthreads();
        bf16x8 af[4], bfr[4];
#pragma unroll
        for (int t = 0; t < 4; t++) {
            af[t]  = *(const bf16x8*)(&As[(wm + t * 16 + l15) * 32 + quad * 8]);
            bfr[t] = *(const bf16x8*)(&Bs[(wn + t * 16 + l15) * 32 + quad * 8]);
        }
#pragma unroll
        for (int i = 0; i < 4; i++)
#pragma unroll
            for (int j = 0; j < 4; j++)
                acc[i][j] = __builtin_amdgcn_mfma_f32_16x16x32_bf16(af[i], bfr[j], acc[i][j], 0, 0, 0);
        __syncthreads();
    }

    // C/D layout: col = lane&15, row = quad*4 + reg
#pragma unroll
    for (int i = 0; i < 4; i++) {
        int row0 = bm * 128 + wm + i * 16 + quad * 4;
#pragma unroll
        for (int j = 0; j < 4; j++) {
            int col = bn * 128 + wn + j * 16 + l15;
            float bv = bias[col];
#pragma unroll
            for (int rr = 0; rr < 4; rr++) {
                int row = row0 + rr;
                float v = acc[i][j][rr] + bv;
                if (EPI == 1) {   // tanh-form GELU: |err| < 1e-3, tolerance 0.115
                    float zz = 1.5957691216f * (v + 0.044715f * v * v * v);  // 2*0.7978845608
                    float t = 1.0f - 2.0f / (__expf(zz) + 1.0f);             // tanh(zz/... )
                    v = 0.5f * v * (1.0f + t);
                }
                if (EPI == 2) v += b2f(res[(size_t)row * 512 + col]);
                if (OF32) ((float*)C)[(size_t)row * N + col] = v;
                else      ((u16*)C)[(size_t)row * N + col] = f2b(v);
            }
        }
    }
}

// ---------------- windowed attention: one block per (window, head), online softmax ----------------
__global__ __launch_bounds__(128) void attn_k(const u16* __restrict__ Q, const u16* __restrict__ Km,
                                              const u16* __restrict__ V, const float* __restrict__ table,
                                              u16* __restrict__ ctx) {
    __shared__ float Ks[100 * 36];   // stride 36: float4-aligned rows
    __shared__ float Vs[100 * 36];
    __shared__ int koff[100];
    __shared__ int regk[100];
    int bid = blockIdx.x;
    int win = bid >> 4, head = bid & 15;
    int w48 = win % 48;
    int wh = w48 / 6, ww = w48 - wh * 6;
    int tid = threadIdx.x;
    size_t base = (size_t)win * 100 * 512 + head * 32;
    for (int vi = tid; vi < 400; vi += 128) {
        int kk = vi >> 2, d0 = (vi & 3) * 8;
        uint4 dk = *(const uint4*)(Km + base + (size_t)kk * 512 + d0);
        uint4 dv = *(const uint4*)(V + base + (size_t)kk * 512 + d0);
        const u16* ku = (const u16*)&dk; const u16* vu = (const u16*)&dv;
#pragma unroll
        for (int t = 0; t < 8; t++) { Ks[kk * 36 + d0 + t] = b2f(ku[t]); Vs[kk * 36 + d0 + t] = b2f(vu[t]); }
    }
    if (tid < 100) {
        int ki = tid / 10, kj = tid - ki * 10;
        koff[tid] = ki * 19 + kj;
        int rh = (wh == 7) ? (ki < 5 ? 1 : 2) : 0;
        int rw = (ww == 5) ? (kj < 5 ? 1 : 2) : 0;
        regk[tid] = rh * 4 + rw;
    }
    __syncthreads();
    int q = tid;
    if (q >= 100) return;
    float4 qr4[8];
    {
        const u16* qp = Q + base + (size_t)q * 512;
#pragma unroll
        for (int t = 0; t < 4; t++) {
            uint4 dq = *(const uint4*)(qp + t * 8);
            const u16* qu = (const u16*)&dq;
            qr4[2*t]   = make_float4(b2f(qu[0]), b2f(qu[1]), b2f(qu[2]), b2f(qu[3]));
            qr4[2*t+1] = make_float4(b2f(qu[4]), b2f(qu[5]), b2f(qu[6]), b2f(qu[7]));
#pragma unroll
            for (int e = 0; e < 4; e++) {
                ((float*)&qr4[2*t])[e]   *= 0.17677669529663689f;  // 1/sqrt(32)
                ((float*)&qr4[2*t+1])[e] *= 0.17677669529663689f;
            }
        }
    }
    int qoff = koff[q], regq = regk[q];
    const float* tq = table + (qoff + 180) * 16 + head;
    float m = -1e30f, l = 0.f;
    float2 o2[16];
#pragma unroll
    for (int i = 0; i < 16; i++) o2[i] = make_float2(0.f, 0.f);
    for (int k = 0; k < 100; k++) {
        const float4* kr = (const float4*)&Ks[k * 36];
        float a = 0.f;
#pragma unroll
        for (int t = 0; t < 8; t++) {
            float4 kv = kr[t];
            a = fmaf(qr4[t].x, kv.x, a); a = fmaf(qr4[t].y, kv.y, a);
            a = fmaf(qr4[t].z, kv.z, a); a = fmaf(qr4[t].w, kv.w, a);
        }
        a += tq[-koff[k] * 16];
        a += (regk[k] != regq) ? -100.f : 0.f;
        float mn = fmaxf(m, a);
        float alpha = __expf(m - mn);
        float p = __expf(a - mn);
        l = l * alpha + p;
        const float2* vr = (const float2*)&Vs[k * 36];
#pragma unroll
        for (int i = 0; i < 16; i++) {
            float2 vv = vr[i];
            o2[i].x = fmaf(o2[i].x, alpha, p * vv.x);
            o2[i].y = fmaf(o2[i].y, alpha, p * vv.y);
        }
        m = mn;
    }
    float inv = 1.0f / l;
    u16* cp = ctx + base + (size_t)q * 512;
#pragma unroll
    for (int t = 0; t < 4; t++) {
        uint4 ov; u16* ou = (u16*)&ov;
#pragma unroll
        for (int e = 0; e < 4; e++) {
            ou[2*e]   = f2b(o2[t*4 + e].x * inv);
            ou[2*e+1] = f2b(o2[t*4 + e].y * inv);
        }
        *(uint4*)(cp + t * 8) = ov;
    }
}

extern "C" void kernel_launch(void* const* d_in, const int* in_sizes, int n_in,
                              void* d_out, int out_size, void* d_ws, size_t ws_size,
                              hipStream_t stream) {
    const float* hidden = (const float*)d_in[0];
    const float* ln1_g  = (const float*)d_in[1];
    const float* ln1_b  = (const float*)d_in[2];
    const float* wq = (const float*)d_in[3];  const float* bq = (const float*)d_in[4];
    const float* wk = (const float*)d_in[5];  const float* bk = (const float*)d_in[6];
    const float* wv = (const float*)d_in[7];  const float* bv = (const float*)d_in[8];
    const float* wo = (const float*)d_in[9];  const float* bo = (const float*)d_in[10];
    const float* rel = (const float*)d_in[11];
    const float* ln2_g = (const float*)d_in[12];
    const float* ln2_b = (const float*)d_in[13];
    const float* w1 = (const float*)d_in[14]; const float* b1 = (const float*)d_in[15];
    const float* w2 = (const float*)d_in[16]; const float* b2 = (const float*)d_in[17];

    // ws: R0,R1,Rh = 3*NTC bf16 (118MB, proven R2) + weights. d_out doubles as V / ln2y park.
    //   R0: win -> ctx -> h1 chunk (9600x2048 == NTC)
    //   R1: q -> attn_out
    //   Rh: k -> hs
    //   d_out lo-half (bf16): v -> ln2y ; fp32 out written in REVERSE chunk order
    const size_t NTC = 38400ull * 512;
    u16* ws = (u16*)d_ws;
    u16* R0 = ws;
    u16* R1 = ws + NTC;
    u16* Rh = ws + 2 * NTC;
    u16* wqt = ws + 3 * NTC;
    u16* wkt = wqt + 512 * 512;
    u16* wvt = wkt + 512 * 512;
    u16* wot = wvt + 512 * 512;
    u16* w1t = wot + 512 * 512;      // (2048,512)
    u16* w2t = w1t + 1048576;        // (512,2048)
    u16* dlo = (u16*)d_out;          // v, then ln2y (bf16)
    float* outp = (float*)d_out;

    transpose_k<<<dim3(16, 16), 256, 0, stream>>>(wq, wqt, 512, 512);
    transpose_k<<<dim3(16, 16), 256, 0, stream>>>(wk, wkt, 512, 512);
    transpose_k<<<dim3(16, 16), 256, 0, stream>>>(wv, wvt, 512, 512);
    transpose_k<<<dim3(16, 16), 256, 0, stream>>>(wo, wot, 512, 512);
    transpose_k<<<dim3(16, 64), 256, 0, stream>>>(w1, w1t, 512, 2048);
    transpose_k<<<dim3(64, 16), 256, 0, stream>>>(w2, w2t, 2048, 512);

    ln1win_k<<<9600, 256, 0, stream>>>(hidden, ln1_g, ln1_b, R0 /*win*/);

    gemm_k<0, 0><<<dim3(300, 4), 256, 0, stream>>>(R0, wqt, bq, nullptr, R1 /*q*/, 38400, 512, 512);
    gemm_k<0, 0><<<dim3(300, 4), 256, 0, stream>>>(R0, wkt, bk, nullptr, Rh /*k*/, 38400, 512, 512);
    gemm_k<0, 0><<<dim3(300, 4), 256, 0, stream>>>(R0, wvt, bv, nullptr, dlo /*v*/, 38400, 512, 512);

    attn_k<<<6144, 128, 0, stream>>>(R1, Rh, dlo, rel, R0 /*ctx*/);

    gemm_k<0, 0><<<dim3(300, 4), 256, 0, stream>>>(R0, wot, bo, nullptr, R1 /*attn_out*/, 38400, 512, 512);

    resid2_k<<<9600, 256, 0, stream>>>(hidden, R1, ln2_g, ln2_b, Rh /*hs*/, dlo /*ln2y*/);

    // FFN chunks in REVERSE order so fp32 out writes never clobber unread bf16 ln2y rows:
    // chunk mc reads ln2y bf16 bytes [mc*9.83MB, +9.83MB); writes fp32 [mc*19.66MB, +19.66MB).
    for (int mc = 3; mc >= 0; mc--) {
        size_t roff = (size_t)mc * 9600 * 512;
        gemm_k<1, 0><<<dim3(75, 16), 256, 0, stream>>>(dlo + roff, w1t, b1, nullptr, R0 /*h1*/,
                                                       9600, 2048, 512);
        gemm_k<2, 1><<<dim3(75, 4), 256, 0, stream>>>(R0, w2t, b2, Rh + roff, outp + roff,
                                                      9600, 512, 2048);
    }
}